// Round 1
// baseline (620.074 us; speedup 1.0000x reference)
//
#include <hip/hip_runtime.h>
#include <math.h>

#define BATCH 16
#define CH 64
#define HH 256
#define WW 256
#define HW (HH*WW)     // 65536
#define HW4 (HW/4)     // 16384
#define HIDDEN 32
#define GRP 4          // batches per pipeline group (x chunk = 67 MB, L3-resident)
#define NGRP (BATCH/GRP)
#define K2_BPB 256     // K2 blocks per batch (16x16 tiles)

typedef float nfloat4 __attribute__((ext_vector_type(4)));

// K1 (grouped, channel-split x4): per-pixel channel reductions over 4 batches.
// Each thread reduces 16 channels of one float4-pixel; 4 threads/pixel combine via LDS.
// 16 independent float4 loads in flight per thread -> ~2x the memory-level
// parallelism of the old unroll-8 version.
__global__ __launch_bounds__(256) void msa_k1_reduce(
    const float* __restrict__ x, const float* __restrict__ wr,
    float* __restrict__ mm, float* __restrict__ xrp, int b0)
{
    __shared__ float part[3][64][13];   // +1 pad: conflict-free 12-float records
    int t = threadIdx.x;
    int p = t & 63;          // pixel slot within block (wave-contiguous)
    int q = t >> 6;          // channel quarter (== wave id)
    int i4 = blockIdx.x * 64 + p;       // [0, GRP*HW4)
    int bl = i4 >> 14;                   // / HW4
    int p4 = i4 & (HW4 - 1);
    int b = b0 + bl;
    const float4* xb = (const float4*)x + (size_t)(b * CH + q * 16) * HW4 + p4;
    float sx = 0.f, sy = 0.f, sz = 0.f, sw = 0.f;
    float mx = -3.4e38f, my = -3.4e38f, mz = -3.4e38f, mw = -3.4e38f;
    float rx = 0.f, ry = 0.f, rz = 0.f, rw = 0.f;
    #pragma unroll 16
    for (int c = 0; c < 16; c++) {
        float4 v = xb[(size_t)c * HW4];
        float w = wr[q * 16 + c];
        sx += v.x; sy += v.y; sz += v.z; sw += v.w;
        mx = fmaxf(mx, v.x); my = fmaxf(my, v.y);
        mz = fmaxf(mz, v.z); mw = fmaxf(mw, v.w);
        rx += w * v.x; ry += w * v.y; rz += w * v.z; rw += w * v.w;
    }
    if (q) {
        float* d = part[q - 1][p];
        d[0] = sx; d[1] = sy; d[2] = sz; d[3] = sw;
        d[4] = mx; d[5] = my; d[6] = mz; d[7] = mw;
        d[8] = rx; d[9] = ry; d[10] = rz; d[11] = rw;
    }
    __syncthreads();
    if (q == 0) {
        #pragma unroll
        for (int k = 0; k < 3; k++) {
            const float* d = part[k][p];
            sx += d[0]; sy += d[1]; sz += d[2]; sw += d[3];
            mx = fmaxf(mx, d[4]); my = fmaxf(my, d[5]);
            mz = fmaxf(mz, d[6]); mw = fmaxf(mw, d[7]);
            rx += d[8]; ry += d[9]; rz += d[10]; rw += d[11];
        }
        const float inv = 1.0f / CH;
        size_t o = (size_t)b * HW4 + p4;
        float4 mm0 = {sx * inv, mx, sy * inv, my};
        float4 mm1 = {sz * inv, mz, sw * inv, mw};
        ((float4*)mm)[2 * o]     = mm0;
        ((float4*)mm)[2 * o + 1] = mm1;
        float4 xrv = {rx, ry, rz, rw};
        ((float4*)xrp)[o] = xrv;
    }
}

// K2 (grouped, K3 fused): 3x3 + 5x5 convs over (mean,max), sigmoid, 1x1 fuse,
// scale; writes f plane and accumulates sum_b(f*xr). The last block per batch
// (atomic ticket) runs the channel-attention MLP and writes cw[b,:].
__global__ __launch_bounds__(256) void msa_k2_conv(
    const float* __restrict__ mm, const float* __restrict__ xrp,
    const float* __restrict__ w3, const float* __restrict__ b3,
    const float* __restrict__ w5, const float* __restrict__ b5,
    const float* __restrict__ wf, const float* __restrict__ bf,
    const float* __restrict__ br,
    const float* __restrict__ wc1, const float* __restrict__ bc1,
    const float* __restrict__ wc2, const float* __restrict__ bc2,
    float* __restrict__ fplane, float* __restrict__ sums,
    unsigned* __restrict__ cnt, float* __restrict__ cw, int b0)
{
    __shared__ float sm[2][20][20];   // 16x16 tile + halo 2
    __shared__ float wsum[4];
    __shared__ int lastflag;
    __shared__ float pooledS;
    __shared__ float hsh[HIDDEN];
    int b = b0 + blockIdx.z;
    int h0 = blockIdx.y * 16, w0 = blockIdx.x * 16;
    int tx = threadIdx.x, ty = threadIdx.y;
    int tid = ty * 16 + tx;
    const float2* mb = (const float2*)mm + (size_t)b * HW;
    for (int l = tid; l < 400; l += 256) {
        int lh = l / 20, lw = l % 20;
        int gh = h0 + lh - 2, gw = w0 + lw - 2;
        float vm = 0.f, vx = 0.f;
        if (gh >= 0 && gh < HH && gw >= 0 && gw < WW) {
            float2 v = mb[gh * WW + gw];
            vm = v.x; vx = v.y;
        }
        sm[0][lh][lw] = vm;
        sm[1][lh][lw] = vx;
    }
    __syncthreads();
    float s3 = b3[0];
    #pragma unroll
    for (int kh = 0; kh < 3; kh++)
        #pragma unroll
        for (int kw = 0; kw < 3; kw++)
            s3 += sm[0][ty + 1 + kh][tx + 1 + kw] * w3[kh * 3 + kw]
                + sm[1][ty + 1 + kh][tx + 1 + kw] * w3[9 + kh * 3 + kw];
    float s5 = b5[0];
    #pragma unroll
    for (int kh = 0; kh < 5; kh++)
        #pragma unroll
        for (int kw = 0; kw < 5; kw++)
            s5 += sm[0][ty + kh][tx + kw] * w5[kh * 5 + kw]
                + sm[1][ty + kh][tx + kw] * w5[25 + kh * 5 + kw];
    float a3 = 1.f / (1.f + expf(-s3));
    float a5 = 1.f / (1.f + expf(-s5));
    float fused = wf[0] * a3 + wf[1] * a5 + bf[0];
    float f = 0.2f + 0.8f * fused;
    int gh = h0 + ty, gw = w0 + tx;
    size_t po = (size_t)b * HW + gh * WW + gw;
    fplane[po] = f;
    // wave-shuffle reduction of f*xr (4 waves -> 4 partials -> scalar)
    float v = f * xrp[po];
    #pragma unroll
    for (int off = 32; off > 0; off >>= 1) v += __shfl_down(v, off);
    if ((tid & 63) == 0) wsum[tid >> 6] = v;
    __syncthreads();
    if (tid == 0) {
        float tot = wsum[0] + wsum[1] + wsum[2] + wsum[3];
        atomicAdd(&sums[b], tot);
        __threadfence();
        unsigned old = atomicAdd(&cnt[b], 1u);
        lastflag = (old == K2_BPB - 1) ? 1 : 0;
    }
    __syncthreads();
    if (lastflag) {
        // this is the last block for batch b: all sums contributions are visible
        if (tid == 0) {
            float tot = atomicAdd(&sums[b], 0.0f);   // coherent read
            pooledS = tot * (1.0f / HW) + br[0];
        }
        __syncthreads();
        if (tid < HIDDEN) hsh[tid] = fmaxf(wc1[tid] * pooledS + bc1[tid], 0.f);
        __syncthreads();
        if (tid < CH) {
            float acc = bc2[tid];
            #pragma unroll
            for (int j = 0; j < HIDDEN; j++) acc += wc2[tid * HIDDEN + j] * hsh[j];
            cw[b * CH + tid] = 1.f / (1.f + expf(-acc));
        }
    }
}

// K4 (grouped): out = x * (f * cw + 0.7). x[g] is L3-resident (read by K1(g)
// two dispatches ago, only ~17 MB touched since). Non-temporal stores so the
// out stream doesn't evict the next group's working set.
__global__ __launch_bounds__(256) void msa_k4_out(
    const float* __restrict__ x, const float* __restrict__ fplane,
    const float* __restrict__ cw, float* __restrict__ out, int b0)
{
    int idx = blockIdx.x * 256 + threadIdx.x;   // [0, GRP*CH*HW4)
    size_t base = (size_t)b0 * CH * HW4;
    int p = idx & (HW4 - 1);
    int bc = idx >> 14;         // local b*CH + c
    int bl = bc >> 6;
    int b = b0 + bl;
    float s = cw[b * CH + (bc & 63)];
    float4 xv = ((const float4*)x)[base + idx];
    float4 fv = ((const float4*)fplane)[(size_t)b * HW4 + p];
    nfloat4 o;
    o.x = xv.x * (fv.x * s + 0.7f);
    o.y = xv.y * (fv.y * s + 0.7f);
    o.z = xv.z * (fv.z * s + 0.7f);
    o.w = xv.w * (fv.w * s + 0.7f);
    __builtin_nontemporal_store(o, ((nfloat4*)out) + base + idx);
}

extern "C" void kernel_launch(void* const* d_in, const int* in_sizes, int n_in,
                              void* d_out, int out_size, void* d_ws, size_t ws_size,
                              hipStream_t stream) {
    const float* x   = (const float*)d_in[0];
    const float* w3  = (const float*)d_in[1];
    const float* b3  = (const float*)d_in[2];
    const float* w5  = (const float*)d_in[3];
    const float* b5  = (const float*)d_in[4];
    const float* wf  = (const float*)d_in[5];
    const float* bf  = (const float*)d_in[6];
    const float* wr  = (const float*)d_in[7];
    const float* br  = (const float*)d_in[8];
    const float* wc1 = (const float*)d_in[9];
    const float* bc1 = (const float*)d_in[10];
    const float* wc2 = (const float*)d_in[11];
    const float* bc2 = (const float*)d_in[12];

    float* ws    = (float*)d_ws;
    float* mm    = ws;                               // BATCH*HW*2 (mean,max pairs)
    float* xrp   = ws + (size_t)2 * BATCH * HW;      // BATCH*HW
    float* fpl   = ws + (size_t)3 * BATCH * HW;      // BATCH*HW
    float* sums  = ws + (size_t)4 * BATCH * HW;      // BATCH floats
    unsigned* cnt = (unsigned*)(sums + BATCH);       // BATCH uints (ticket)
    float* cw    = sums + 2 * BATCH;                 // BATCH*CH floats

    (void)hipMemsetAsync(sums, 0, 2 * BATCH * sizeof(float), stream);

    for (int g = 0; g < NGRP; ++g) {
        int b0 = g * GRP;
        msa_k1_reduce<<<GRP * HW4 / 64, 256, 0, stream>>>(x, wr, mm, xrp, b0);
        dim3 g2(WW / 16, HH / 16, GRP);
        msa_k2_conv<<<g2, dim3(16, 16), 0, stream>>>(mm, xrp, w3, b3, w5, b5,
                                                     wf, bf, br, wc1, bc1, wc2, bc2,
                                                     fpl, sums, cnt, cw, b0);
        msa_k4_out<<<GRP * CH * HW4 / 256, 256, 0, stream>>>(x, fpl, cw,
                                                             (float*)d_out, b0);
    }
}